// Round 6
// baseline (199.424 us; speedup 1.0000x reference)
//
#include <hip/hip_runtime.h>

// NCC loss, fused z-sweep, v6 = R1 per-thread structure at higher TLP:
// 256-thread blocks, 16x16 tile, grid 1600 (~6.25 blocks/CU), LDS ~13 KB.
// Per slice: stage -> sync -> xf (9 b64 taps) -> sync -> yf (9 b128+b32) ->
// z-ring -> NCC. 2 barriers/slice (R1-proven hazard structure).

#define TX 16
#define TY 16
#define ZC 20
#define PH 24          // TY+8
#define PW 24          // TX+8
#define XFP 17         // padded float4 row stride (anti 4-way alias)
#define NSTEP 28       // ZC+8
#define NN 160
#define NPLANE (160*160)

__global__ void ncc_zero_ws(float* ws) { ws[0] = 0.0f; }

__global__ __launch_bounds__(256, 6)
void ncc_fused(const float* __restrict__ pred, const float* __restrict__ target,
               float* __restrict__ ws) {
  __shared__ float2 st[PH * PW];       // staged (t,p)          4.6 KB
  __shared__ float4 xf4[PH * XFP];     // x-filt (t,p,t2,p2)    6.5 KB
  __shared__ float  xf1[PH * XFP];     // x-filt tp             1.6 KB
  __shared__ float  wsum[4];

  const int tid = threadIdx.x;
  const int tx = tid & 15;
  const int ty = tid >> 4;             // 0..15

  int b = blockIdx.x;
  const int xt = b % 10; b /= 10;
  const int yt = b % 10; b /= 10;
  const int zc = b % 8;  b /= 8;
  const int x0 = xt * TX, y0 = yt * TY, z0 = zc * ZC;
  const size_t bbase = (size_t)b * (size_t)NN * (size_t)NPLANE;

  float buf[5][9];
  float run0 = 0, run1 = 0, run2 = 0, run3 = 0, run4 = 0;
  #pragma unroll
  for (int f = 0; f < 5; ++f)
    #pragma unroll
    for (int j = 0; j < 9; ++j) buf[f][j] = 0.0f;
  float acc = 0.0f;
  const float inv_kvol = 1.0f / 729.0f;

  for (int s0 = 0; s0 < NSTEP; s0 += 9) {
    #pragma unroll
    for (int pp = 0; pp < 9; ++pp) {
      const int s = s0 + pp;
      if (s < NSTEP) {
        const int zi = z0 - 4 + s;
        const bool zvalid = ((unsigned)zi < NN);    // block-uniform
        float cur0 = 0, cur1 = 0, cur2 = 0, cur3 = 0, cur4 = 0;
        if (zvalid) {
          // ---- stage slice (zero-pad x,y): 576 float2, 256 threads ----
          const size_t zb = bbase + (size_t)zi * (size_t)NPLANE;
          for (int pos = tid; pos < PH * PW; pos += 256) {
            const int yy = pos / PW, xx = pos - yy * PW;
            const int gy = y0 + yy - 4, gx = x0 + xx - 4;
            float tv = 0.0f, pv = 0.0f;
            if ((unsigned)gy < NN && (unsigned)gx < NN) {
              const size_t idx = zb + (size_t)(gy * NN + gx);
              tv = target[idx];
              pv = pred[idx];
            }
            st[pos] = make_float2(tv, pv);
          }
          __syncthreads();   // A: st visible
          // ---- x-filter: 384 outputs, 9 b64 taps each ----
          for (int pos = tid; pos < PH * TX; pos += 256) {
            const int yy = pos >> 4;
            const int xx = pos & 15;
            float s_t = 0, s_p = 0, s_t2 = 0, s_p2 = 0, s_tp = 0;
            #pragma unroll
            for (int dx = 0; dx < 9; ++dx) {
              const float2 v = st[yy * PW + xx + dx];
              s_t += v.x;
              s_p += v.y;
              s_t2 = fmaf(v.x, v.x, s_t2);
              s_p2 = fmaf(v.y, v.y, s_p2);
              s_tp = fmaf(v.x, v.y, s_tp);
            }
            xf4[yy * XFP + xx] = make_float4(s_t, s_p, s_t2, s_p2);
            xf1[yy * XFP + xx] = s_tp;
          }
          __syncthreads();   // B: xf visible; st reads done
          // ---- y-filter: per-thread column, 9 taps ----
          #pragma unroll
          for (int dy = 0; dy < 9; ++dy) {
            const float4 a = xf4[(ty + dy) * XFP + tx];
            const float  c = xf1[(ty + dy) * XFP + tx];
            cur0 += a.x; cur1 += a.y; cur2 += a.z; cur3 += a.w; cur4 += c;
          }
        }
        // ---- z running window + NCC (slot pp compile-time static) ----
        run0 += cur0 - buf[0][pp]; buf[0][pp] = cur0;
        run1 += cur1 - buf[1][pp]; buf[1][pp] = cur1;
        run2 += cur2 - buf[2][pp]; buf[2][pp] = cur2;
        run3 += cur3 - buf[3][pp]; buf[3][pp] = cur3;
        run4 += cur4 - buf[4][pp]; buf[4][pp] = cur4;
        if (s >= 8) {
          const float tavg = run0 * inv_kvol;
          const float pavg = run1 * inv_kvol;
          const float cross = run4 - pavg * run0;
          const float tvar  = run2 - tavg * run0;
          const float pvar  = run3 - pavg * run1;
          acc += (cross * cross) / (tvar * pvar + 1e-5f);
        }
      }
    }
  }

  // ---- reduction: wave shuffle -> LDS -> one atomicAdd per block ----
  #pragma unroll
  for (int off = 32; off > 0; off >>= 1)
    acc += __shfl_down(acc, off, 64);
  if ((tid & 63) == 0) wsum[tid >> 6] = acc;
  __syncthreads();
  if (tid == 0) {
    float tot = wsum[0] + wsum[1] + wsum[2] + wsum[3];
    atomicAdd(ws, tot);
  }
}

__global__ void ncc_finalize(const float* __restrict__ ws, float* __restrict__ out) {
  out[0] = -ws[0] * (1.0f / 8192000.0f);
}

extern "C" void kernel_launch(void* const* d_in, const int* in_sizes, int n_in,
                              void* d_out, int out_size, void* d_ws, size_t ws_size,
                              hipStream_t stream) {
  const float* pred   = (const float*)d_in[0];
  const float* target = (const float*)d_in[1];
  float* out = (float*)d_out;
  float* ws  = (float*)d_ws;

  ncc_zero_ws<<<1, 1, 0, stream>>>(ws);
  // grid: 10 x-tiles * 10 y-tiles * 8 z-chunks * 2 batches = 1600 blocks
  ncc_fused<<<1600, 256, 0, stream>>>(pred, target, ws);
  ncc_finalize<<<1, 1, 0, stream>>>(ws, out);
}

// Round 7
// 118.472 us; speedup vs baseline: 1.6833x; 1.6833x over previous
//
#include <hip/hip_runtime.h>

// NCC loss, fused z-sweep, v7 = R6 geometry, spill-proofed:
//  - slice body instantiated via macro with LITERAL z-ring slot (rule #20:
//    no reliance on #pragma unroll for static buf indexing)
//  - XFP reverted to 16 (unpadded; b128 row reads are at min aliasing)
//  - __launch_bounds__(256) only
// 256 threads, 16x16 tile, z-chunk 20, grid 1600 (~6.25 blocks/CU), LDS ~12.6KB.

#define TX 16
#define TY 16
#define ZC 20
#define PH 24          // TY+8
#define PW 24          // TX+8
#define XFP 16         // float4 row stride (unpadded)
#define NSTEP 28       // ZC+8
#define NN 160
#define NPLANE (160*160)

__global__ void ncc_zero_ws(float* ws) { ws[0] = 0.0f; }

__global__ __launch_bounds__(256)
void ncc_fused(const float* __restrict__ pred, const float* __restrict__ target,
               float* __restrict__ ws) {
  __shared__ float2 st[PH * PW];       // staged (t,p)          4.6 KB
  __shared__ float4 xf4[PH * XFP];     // x-filt (t,p,t2,p2)    6.1 KB
  __shared__ float  xf1[PH * XFP];     // x-filt tp             1.5 KB
  __shared__ float  wsum[4];

  const int tid = threadIdx.x;
  const int tx = tid & 15;
  const int ty = tid >> 4;             // 0..15

  int b = blockIdx.x;
  const int xt = b % 10; b /= 10;
  const int yt = b % 10; b /= 10;
  const int zc = b % 8;  b /= 8;
  const int x0 = xt * TX, y0 = yt * TY, z0 = zc * ZC;
  const size_t bbase = (size_t)b * (size_t)NN * (size_t)NPLANE;

  float buf0[9], buf1[9], buf2[9], buf3[9], buf4[9];
  float run0 = 0, run1 = 0, run2 = 0, run3 = 0, run4 = 0;
  #pragma unroll
  for (int j = 0; j < 9; ++j) { buf0[j]=0; buf1[j]=0; buf2[j]=0; buf3[j]=0; buf4[j]=0; }
  float acc = 0.0f;
  const float inv_kvol = 1.0f / 729.0f;

  // ---- slice body; PP is a LITERAL constant -> buf*[PP] always static ----
#define ZBODY(PP) do {                                                        \
    const int s = s0 + (PP);                                                  \
    if (s < NSTEP) {                                                          \
      const int zi = z0 - 4 + s;                                              \
      const bool zvalid = ((unsigned)zi < NN);    /* block-uniform */         \
      float cur0 = 0, cur1 = 0, cur2 = 0, cur3 = 0, cur4 = 0;                 \
      if (zvalid) {                                                           \
        const size_t zb = bbase + (size_t)zi * (size_t)NPLANE;                \
        for (int pos = tid; pos < PH * PW; pos += 256) {                      \
          const int yy = pos / PW, xx = pos - yy * PW;                        \
          const int gy = y0 + yy - 4, gx = x0 + xx - 4;                       \
          float tv = 0.0f, pv = 0.0f;                                         \
          if ((unsigned)gy < NN && (unsigned)gx < NN) {                       \
            const size_t idx = zb + (size_t)(gy * NN + gx);                   \
            tv = target[idx];                                                 \
            pv = pred[idx];                                                   \
          }                                                                   \
          st[pos] = make_float2(tv, pv);                                      \
        }                                                                     \
        __syncthreads();   /* A: st visible */                                \
        for (int pos = tid; pos < PH * TX; pos += 256) {                      \
          const int yy = pos >> 4;                                            \
          const int xx = pos & 15;                                            \
          float s_t = 0, s_p = 0, s_t2 = 0, s_p2 = 0, s_tp = 0;               \
          _Pragma("unroll")                                                   \
          for (int dx = 0; dx < 9; ++dx) {                                    \
            const float2 v = st[yy * PW + xx + dx];                           \
            s_t += v.x;                                                       \
            s_p += v.y;                                                       \
            s_t2 = fmaf(v.x, v.x, s_t2);                                      \
            s_p2 = fmaf(v.y, v.y, s_p2);                                      \
            s_tp = fmaf(v.x, v.y, s_tp);                                      \
          }                                                                   \
          xf4[yy * XFP + xx] = make_float4(s_t, s_p, s_t2, s_p2);             \
          xf1[yy * XFP + xx] = s_tp;                                          \
        }                                                                     \
        __syncthreads();   /* B: xf visible; st reads done */                 \
        _Pragma("unroll")                                                     \
        for (int dy = 0; dy < 9; ++dy) {                                      \
          const float4 a = xf4[(ty + dy) * XFP + tx];                         \
          const float  c = xf1[(ty + dy) * XFP + tx];                         \
          cur0 += a.x; cur1 += a.y; cur2 += a.z; cur3 += a.w; cur4 += c;      \
        }                                                                     \
      }                                                                       \
      run0 += cur0 - buf0[(PP)]; buf0[(PP)] = cur0;                           \
      run1 += cur1 - buf1[(PP)]; buf1[(PP)] = cur1;                           \
      run2 += cur2 - buf2[(PP)]; buf2[(PP)] = cur2;                           \
      run3 += cur3 - buf3[(PP)]; buf3[(PP)] = cur3;                           \
      run4 += cur4 - buf4[(PP)]; buf4[(PP)] = cur4;                           \
      if (s >= 8) {                                                           \
        const float tavg = run0 * inv_kvol;                                   \
        const float pavg = run1 * inv_kvol;                                   \
        const float cross = run4 - pavg * run0;                               \
        const float tvar  = run2 - tavg * run0;                               \
        const float pvar  = run3 - pavg * run1;                               \
        acc += (cross * cross) / (tvar * pvar + 1e-5f);                       \
      }                                                                       \
    }                                                                         \
  } while (0)

  for (int s0 = 0; s0 < NSTEP; s0 += 9) {
    ZBODY(0); ZBODY(1); ZBODY(2); ZBODY(3); ZBODY(4);
    ZBODY(5); ZBODY(6); ZBODY(7); ZBODY(8);
  }
#undef ZBODY

  // ---- reduction: wave shuffle -> LDS -> one atomicAdd per block ----
  #pragma unroll
  for (int off = 32; off > 0; off >>= 1)
    acc += __shfl_down(acc, off, 64);
  if ((tid & 63) == 0) wsum[tid >> 6] = acc;
  __syncthreads();
  if (tid == 0) {
    float tot = wsum[0] + wsum[1] + wsum[2] + wsum[3];
    atomicAdd(ws, tot);
  }
}

__global__ void ncc_finalize(const float* __restrict__ ws, float* __restrict__ out) {
  out[0] = -ws[0] * (1.0f / 8192000.0f);
}

extern "C" void kernel_launch(void* const* d_in, const int* in_sizes, int n_in,
                              void* d_out, int out_size, void* d_ws, size_t ws_size,
                              hipStream_t stream) {
  const float* pred   = (const float*)d_in[0];
  const float* target = (const float*)d_in[1];
  float* out = (float*)d_out;
  float* ws  = (float*)d_ws;

  ncc_zero_ws<<<1, 1, 0, stream>>>(ws);
  // grid: 10 x-tiles * 10 y-tiles * 8 z-chunks * 2 batches = 1600 blocks
  ncc_fused<<<1600, 256, 0, stream>>>(pred, target, ws);
  ncc_finalize<<<1, 1, 0, stream>>>(ws, out);
}